// Round 9
// baseline (495.643 us; speedup 1.0000x reference)
//
#include <hip/hip_runtime.h>
#include <math.h>

#define D_DIM 3072
#define H_DIM 1024
#define Z_DIM 32
#define BATCH 128
#define NNEI 32
#define NROWS (BATCH * NNEI) /* 4096 */
#define MENC (NROWS + BATCH) /* 4224 */

typedef __attribute__((ext_vector_type(8))) short short8;
typedef __attribute__((ext_vector_type(4))) float f32x4;
typedef unsigned short ushortT;

__device__ __forceinline__ unsigned short f2bf(float f) {
  union { float f; unsigned int u; } v; v.f = f;
  unsigned int r = v.u + 0x7FFFu + ((v.u >> 16) & 1u);
  return (unsigned short)(r >> 16);
}
__device__ __forceinline__ float bf2f(unsigned short b) {
  union { unsigned int u; float f; } v; v.u = ((unsigned int)b) << 16;
  return v.f;
}

enum { EP_RELU = 0, EP_BIAS = 1, EP_PART = 2, EP_LOSS = 3, EP_MASK1 = 4 };

// R18: register-direct GEMM -- NO LDS, NO barriers.
// R17 post-mortem: per-block serial pinned at ~5100 cyc/BK32-tile across
// SIX structures (R0,R11-R15), with NOTHING saturated at the measured
// 1700 cyc/tile-step/CU (DS 22%, L2 ~17%, MFMA 14%). Common ingredients of
// all six: LDS staging + per-tile barriers. Both removed here.
// Mechanism: the MFMA A/B fragment layout (lane -> row=l&15, k=(l>>4)*8)
// is byte-identical to the coalesced 16-row global load pattern -- each
// wave loads its fragments DIRECTLY global->VGPR. Double-buffered named
// frag regs (constant indices post-unroll; rule 20 safe) give the compiler
// precise per-register vmcnt; latency hidden by 12 independent waves/CU.
// Reuse is served by L1/L2 (intra-block wave pairs share frags -> L1;
// cross-block tiles share panels -> L2 + XCD swizzle).
// Per wave per BK32 tile-step: 4+NF short8 loads, 4*NF MFMAs.
// A: MxK bf16 row-major, BT: NxK bf16. M%128==0, N%TN==0, Ks%32==0.
template <int MODE, int TN>
__global__ __launch_bounds__(256) __attribute__((amdgpu_waves_per_eu(3)))
void gemmr(
    const ushortT* __restrict__ A, const ushortT* __restrict__ BT,
    const float* __restrict__ bias, ushortT* __restrict__ C,
    float* __restrict__ P, int M, int N, int K, int Ks,
    const ushortT* __restrict__ xa,    // EP_LOSS: M x N bf16 (x_nn)
    const float* __restrict__ wrow,    // EP_LOSS: per-row weight
    float* __restrict__ out) {
  constexpr int NF = TN / 32;   // 4 (TN=128), 2 (TN=64), 1 (TN=32)

  const int t = threadIdx.x;
  const int wave = t >> 6;
  const int lane = t & 63;
  const int quad = lane >> 4;
  const int lm = lane & 15;

  // XCD-bijective swizzle (FETCH 105->42MB). Only when nwg%8==0.
  int id = blockIdx.y * gridDim.x + blockIdx.x;
  const int nwg = gridDim.x * gridDim.y;
  if ((nwg & 7) == 0) id = (id & 7) * (nwg >> 3) + (id >> 3);
  const int bm = (id / gridDim.x) * 128;
  const int bn = (id % gridDim.x) * TN;

  const int koff = blockIdx.z * Ks;
  const int wr = (wave >> 1) * 64;
  const int wc = (wave & 1) * (TN / 2);

  f32x4 acc[4][NF];
#pragma unroll
  for (int i = 0; i < 4; ++i)
#pragma unroll
    for (int j = 0; j < NF; ++j) acc[i][j] = (f32x4)0.f;

  // fragment base: lane -> (row-in-16 = lane&15, k-quad = (lane>>4)*8)
  const int fr = lane & 15;
  const int fk = (lane >> 4) * 8;
  const ushortT* pa = A + (size_t)(bm + wr + fr) * K + koff + fk;
  const ushortT* pb = BT + (size_t)(bn + wc + fr) * K + koff + fk;
  const size_t r16 = (size_t)16 * K;

  short8 aX[4], bX[NF], aY[4], bY[NF];

#define LOADF(aa, bb, kk)                                                  \
  {                                                                        \
    const size_t o = (size_t)(kk) * 32;                                    \
    _Pragma("unroll")                                                      \
    for (int mt = 0; mt < 4; ++mt)                                         \
      aa[mt] = *(const short8*)(pa + (size_t)mt * r16 + o);                \
    _Pragma("unroll")                                                      \
    for (int nt = 0; nt < NF; ++nt)                                        \
      bb[nt] = *(const short8*)(pb + (size_t)nt * r16 + o);                \
  }
#define DOMFMA(aa, bb)                                                     \
  {                                                                        \
    _Pragma("unroll")                                                      \
    for (int mt = 0; mt < 4; ++mt)                                         \
      _Pragma("unroll")                                                    \
      for (int nt = 0; nt < NF; ++nt)                                      \
        acc[mt][nt] = __builtin_amdgcn_mfma_f32_16x16x32_bf16(             \
            aa[mt], bb[nt], acc[mt][nt], 0, 0, 0);                         \
  }

  const int nk = Ks / 32;
  LOADF(aX, bX, 0);
  for (int t0 = 0; t0 < nk; t0 += 2) {
    if (t0 + 1 < nk) LOADF(aY, bY, t0 + 1);
    DOMFMA(aX, bX);
    if (t0 + 2 < nk) LOADF(aX, bX, t0 + 2);
    if (t0 + 1 < nk) DOMFMA(aY, bY);
  }
#undef LOADF
#undef DOMFMA

  // C/D layout: col = lane&15, row = quad*4 + reg
  if (MODE == EP_LOSS) {
    __shared__ float red[256];
    float lsum = 0.f;
#pragma unroll
    for (int mt = 0; mt < 4; ++mt) {
#pragma unroll
      for (int r = 0; r < 4; ++r) {
        const int row = bm + wr + mt * 16 + quad * 4 + r;
        const float w = wrow[row];
        const ushortT* xr = xa + (size_t)row * N;
        float rs = 0.f;
#pragma unroll
        for (int nt = 0; nt < NF; ++nt) {
          const int col = bn + wc + nt * 16 + lm;
          const float d = bf2f(xr[col]) - (acc[mt][nt][r] + bias[col]);
          rs = fmaf(d, d, rs);
        }
        lsum = fmaf(w, rs, lsum);
      }
    }
    __syncthreads();
    red[t] = lsum;
    __syncthreads();
    for (int st = 128; st > 0; st >>= 1) {
      if (t < st) red[t] += red[t + st];
      __syncthreads();
    }
    if (t == 0) atomicAdd(out, red[0] * (1.0f / (float)NROWS));
  } else if (MODE == EP_PART) {
#pragma unroll
    for (int mt = 0; mt < 4; ++mt)
#pragma unroll
      for (int r = 0; r < 4; ++r) {
        const int row = bm + wr + mt * 16 + quad * 4 + r;
#pragma unroll
        for (int nt = 0; nt < NF; ++nt) {
          const int col = bn + wc + nt * 16 + lm;
          P[((size_t)blockIdx.z * M + row) * N + col] = acc[mt][nt][r];
        }
      }
  } else {
#pragma unroll
    for (int mt = 0; mt < 4; ++mt)
#pragma unroll
      for (int r = 0; r < 4; ++r) {
        const int row = bm + wr + mt * 16 + quad * 4 + r;
#pragma unroll
        for (int nt = 0; nt < NF; ++nt) {
          const int col = bn + wc + nt * 16 + lm;
          float v = acc[mt][nt][r] + bias[col];
          if (MODE == EP_RELU) v = fmaxf(v, 0.f);
          C[(size_t)row * N + col] = f2bf(v);
        }
      }
  }
}

// K=32 single-tile register-direct GEMM (dec L1). EP_MASK1 fuses the
// frozen-mask apply: all 16 rows of an m-tile share ONE center row, so
// U1c = z_center @ Wd1 is one broadcast A-fragment + 1 extra MFMA per
// (mt,nt); epilogue emits A2 = (U1c+bias>0) ? bf16(U1+bias) : 0 for
// neighbor blocks, relu for center blocks (bm >= NROWS).
template <int MODE, int TN>
__global__ __launch_bounds__(256) void gemm_sbr(
    const ushortT* __restrict__ A, const ushortT* __restrict__ BT,
    const float* __restrict__ bias, ushortT* __restrict__ C,
    int M, int N, int K,   // K must be 32
    const ushortT* __restrict__ xa, const float* __restrict__ wrow,
    float* __restrict__ out) {
  constexpr int NF = TN / 32;

  const int t = threadIdx.x;
  const int wave = t >> 6;
  const int lane = t & 63;
  const int quad = lane >> 4;
  const int lm = lane & 15;

  int id = blockIdx.y * gridDim.x + blockIdx.x;
  const int nwg = gridDim.x * gridDim.y;
  if ((nwg & 7) == 0) id = (id & 7) * (nwg >> 3) + (id >> 3);
  const int bm = (id / gridDim.x) * 128;
  const int bn = (id % gridDim.x) * TN;

  const int wr = (wave >> 1) * 64;
  const int wc = (wave & 1) * (TN / 2);

  const int fr = lane & 15;
  const int fk = (lane >> 4) * 8;
  const ushortT* pa = A + (size_t)(bm + wr + fr) * K + fk;
  const ushortT* pb = BT + (size_t)(bn + wc + fr) * K + fk;
  const size_t r16 = (size_t)16 * K;

  short8 af[4], bf[NF];
#pragma unroll
  for (int mt = 0; mt < 4; ++mt)
    af[mt] = *(const short8*)(pa + (size_t)mt * r16);
#pragma unroll
  for (int nt = 0; nt < NF; ++nt)
    bf[nt] = *(const short8*)(pb + (size_t)nt * r16);

  f32x4 acc[4][NF];
#pragma unroll
  for (int i = 0; i < 4; ++i)
#pragma unroll
    for (int j = 0; j < NF; ++j) acc[i][j] = (f32x4)0.f;
#pragma unroll
  for (int mt = 0; mt < 4; ++mt)
#pragma unroll
    for (int nt = 0; nt < NF; ++nt)
      acc[mt][nt] = __builtin_amdgcn_mfma_f32_16x16x32_bf16(
          af[mt], bf[nt], acc[mt][nt], 0, 0, 0);

  // mask GEMM: U1c = z_center @ Wd1 (broadcast A-frag)
  f32x4 acc2[4][NF];
  if (MODE == EP_MASK1) {
#pragma unroll
    for (int i = 0; i < 4; ++i)
#pragma unroll
      for (int j = 0; j < NF; ++j) acc2[i][j] = (f32x4)0.f;
    if (bm < NROWS) {
      short8 az[4];
#pragma unroll
      for (int mt = 0; mt < 4; ++mt) {
        const int cz = NROWS + ((bm + wr + mt * 16) >> 5);
        az[mt] = *(const short8*)(A + (size_t)cz * K + fk);
      }
#pragma unroll
      for (int mt = 0; mt < 4; ++mt)
#pragma unroll
        for (int nt = 0; nt < NF; ++nt)
          acc2[mt][nt] = __builtin_amdgcn_mfma_f32_16x16x32_bf16(
              az[mt], bf[nt], acc2[mt][nt], 0, 0, 0);
    }
  }

  if (MODE == EP_MASK1) {
    const bool nb = (bm < NROWS);
#pragma unroll
    for (int mt = 0; mt < 4; ++mt)
#pragma unroll
      for (int r = 0; r < 4; ++r) {
        const int row = bm + wr + mt * 16 + quad * 4 + r;
#pragma unroll
        for (int nt = 0; nt < NF; ++nt) {
          const int col = bn + wc + nt * 16 + lm;
          const float v = acc[mt][nt][r] + bias[col];
          ushortT o;
          if (nb) {
            const float m = acc2[mt][nt][r] + bias[col];
            o = (m > 0.f) ? f2bf(v) : (ushortT)0;
          } else {
            o = f2bf(fmaxf(v, 0.f));
          }
          C[(size_t)row * N + col] = o;
        }
      }
  } else {
#pragma unroll
    for (int mt = 0; mt < 4; ++mt)
#pragma unroll
      for (int r = 0; r < 4; ++r) {
        const int row = bm + wr + mt * 16 + quad * 4 + r;
#pragma unroll
        for (int nt = 0; nt < NF; ++nt) {
          const int col = bn + wc + nt * 16 + lm;
          float v = acc[mt][nt][r] + bias[col];
          if (MODE == EP_RELU) v = fmaxf(v, 0.f);
          C[(size_t)row * N + col] = f2bf(v);
        }
      }
  }
}

// sum split-K fp32 partials + bias (+optional relu) -> bf16. N power of 2.
template <int S, int RELU>
__global__ __launch_bounds__(256) void reduce_lin(
    const float* __restrict__ P, const float* __restrict__ bias,
    ushortT* __restrict__ outp, int MN, int Nmask) {
  const int i4 = (blockIdx.x * 256 + threadIdx.x) * 4;
  if (i4 >= MN) return;
  float4 s = *(const float4*)(P + i4);
#pragma unroll
  for (int k = 1; k < S; ++k) {
    const float4 q = *(const float4*)(P + (size_t)k * MN + i4);
    s.x += q.x; s.y += q.y; s.z += q.z; s.w += q.w;
  }
  const float4 b = *(const float4*)(bias + (i4 & Nmask));
  float vx = s.x + b.x, vy = s.y + b.y, vz = s.z + b.z, vw = s.w + b.w;
  if (RELU) {
    vx = fmaxf(vx, 0.f); vy = fmaxf(vy, 0.f);
    vz = fmaxf(vz, 0.f); vw = fmaxf(vw, 0.f);
  }
  ushort4 o;
  o.x = f2bf(vx); o.y = f2bf(vy); o.z = f2bf(vz); o.w = f2bf(vw);
  *(ushort4*)(outp + i4) = o;
}

// Fused split-K reduce + frozen-mask apply for dec L2 (R16).
// t2 = (U2[center]>0) ? bf16(U2) : 0 for the NROWS neighbor rows; U2 (own
// row AND center row) re-summed from the S partial planes + bias. Center
// reads 32x-reused -> L2-hot. U2 never materialized.
template <int S>
__global__ __launch_bounds__(256) void reduce_lin_mask(
    const float* __restrict__ P, const float* __restrict__ bias,
    ushortT* __restrict__ outp, int MN /* NROWS*H */, int MNfull /* MENC*H */) {
  const int i4 = (blockIdx.x * 256 + threadIdx.x) * 4;
  if (i4 >= MN) return;
  const int r = i4 >> 10;
  const int c = i4 & 1023;
  const size_t ci = (((size_t)(NROWS + (r >> 5))) << 10) + c;
  float4 s = *(const float4*)(P + i4);
  float4 sc = *(const float4*)(P + ci);
#pragma unroll
  for (int k = 1; k < S; ++k) {
    const float4 q = *(const float4*)(P + (size_t)k * MNfull + i4);
    const float4 qc = *(const float4*)(P + (size_t)k * MNfull + ci);
    s.x += q.x; s.y += q.y; s.z += q.z; s.w += q.w;
    sc.x += qc.x; sc.y += qc.y; sc.z += qc.z; sc.w += qc.w;
  }
  const float4 b = *(const float4*)(bias + c);
  const float ux = s.x + b.x, uy = s.y + b.y, uz = s.z + b.z, uw = s.w + b.w;
  const float mx = sc.x + b.x, my = sc.y + b.y, mz = sc.z + b.z,
              mw = sc.w + b.w;
  ushort4 o;
  o.x = (mx > 0.f) ? f2bf(ux) : (ushortT)0;
  o.y = (my > 0.f) ? f2bf(uy) : (ushortT)0;
  o.z = (mz > 0.f) ? f2bf(uz) : (ushortT)0;
  o.w = (mw > 0.f) ? f2bf(uw) : (ushortT)0;
  *(ushort4*)(outp + i4) = o;
}

// Fused prep: x fp32 -> bf16 A_enc; per-(b,n) weights from dist^2; zero out[0].
__global__ __launch_bounds__(256) void prep_kernel(
    const float* __restrict__ x_c, const float* __restrict__ x_nn,
    ushortT* __restrict__ A_enc, float* __restrict__ wbuf, float* __restrict__ out) {
  const int i = blockIdx.x;
  const int t = threadIdx.x;
  if (i < NROWS) {
    const float* src = x_nn + (size_t)i * D_DIM;
    const float* ctr = x_c + (size_t)(i >> 5) * D_DIM;
    ushortT* dst = A_enc + (size_t)i * D_DIM;
    float s = 0.f;
    for (int d = t * 4; d < D_DIM; d += 1024) {
      const float4 v = *(const float4*)(src + d);
      const float4 c = *(const float4*)(ctr + d);
      ushort4 o;
      o.x = f2bf(v.x); o.y = f2bf(v.y); o.z = f2bf(v.z); o.w = f2bf(v.w);
      *(ushort4*)(dst + d) = o;
      const float dx = v.x - c.x, dy = v.y - c.y, dz = v.z - c.z, dw = v.w - c.w;
      s += dx * dx + dy * dy + dz * dz + dw * dw;
    }
    __shared__ float red[256];
    red[t] = s;
    __syncthreads();
    for (int st = 128; st > 0; st >>= 1) {
      if (t < st) red[t] += red[t + st];
      __syncthreads();
    }
    if (t == 0) {
      wbuf[i] = (red[0] > 1e-24f) ? 1.0f : 0.5f;
      if (i == 0) out[0] = 0.f;
    }
  } else {
    const int r = i - NROWS;
    const float* src = x_c + (size_t)r * D_DIM;
    ushortT* dst = A_enc + (size_t)i * D_DIM;
    for (int d = t * 4; d < D_DIM; d += 1024) {
      const float4 v = *(const float4*)(src + d);
      ushort4 o;
      o.x = f2bf(v.x); o.y = f2bf(v.y); o.z = f2bf(v.z); o.w = f2bf(v.w);
      *(ushort4*)(dst + d) = o;
    }
  }
}

// Batched transpose+cast of all six weights: W (KxN f32) -> WT (NxK bf16).
// Coalesced write phase: thread -> (n = tid>>3, kq = tid&7), each emits a
// ushort4 => 32-thread n-rows write 256B contiguous.
__global__ __launch_bounds__(256) void trans_all(
    const float* __restrict__ We1, const float* __restrict__ We2,
    const float* __restrict__ We3, const float* __restrict__ Wd1,
    const float* __restrict__ Wd2, const float* __restrict__ Wd3,
    ushortT* __restrict__ We1T, ushortT* __restrict__ We2T,
    ushortT* __restrict__ We3T, ushortT* __restrict__ Wd1T,
    ushortT* __restrict__ Wd2T, ushortT* __restrict__ Wd3T) {
  const int b = blockIdx.x;
  const float* W; ushortT* WT; int K, N, loc;
  if (b < 3072)      { W = We1; WT = We1T; K = 3072; N = 1024; loc = b; }
  else if (b < 4096) { W = We2; WT = We2T; K = 1024; N = 1024; loc = b - 3072; }
  else if (b < 4128) { W = We3; WT = We3T; K = 1024; N = 32;   loc = b - 4096; }
  else if (b < 4160) { W = Wd1; WT = Wd1T; K = 32;   N = 1024; loc = b - 4128; }
  else if (b < 5184) { W = Wd2; WT = Wd2T; K = 1024; N = 1024; loc = b - 4160; }
  else               { W = Wd3; WT = Wd3T; K = 1024; N = 3072; loc = b - 5184; }
  const int ntiles = N >> 5;
  const int n0 = (loc % ntiles) * 32;
  const int k0 = (loc / ntiles) * 32;
  __shared__ float tile[32][33];
  const int tx = threadIdx.x & 31;
  const int ty = threadIdx.x >> 5;
  for (int i = ty; i < 32; i += 8)
    tile[i][tx] = W[(size_t)(k0 + i) * N + n0 + tx];
  __syncthreads();
  const int n = threadIdx.x >> 3;
  const int kq = (threadIdx.x & 7) * 4;
  ushort4 o;
  o.x = f2bf(tile[kq + 0][n]);
  o.y = f2bf(tile[kq + 1][n]);
  o.z = f2bf(tile[kq + 2][n]);
  o.w = f2bf(tile[kq + 3][n]);
  *(ushort4*)(WT + (size_t)(n0 + n) * K + k0 + kq) = o;
}

extern "C" void kernel_launch(void* const* d_in, const int* in_sizes, int n_in,
                              void* d_out, int out_size, void* d_ws, size_t ws_size,
                              hipStream_t stream) {
  const float* x_c = (const float*)d_in[0];
  const float* x_nn = (const float*)d_in[1];
  const float* We1 = (const float*)d_in[2];
  const float* be1 = (const float*)d_in[3];
  const float* We2 = (const float*)d_in[4];
  const float* be2 = (const float*)d_in[5];
  const float* We3 = (const float*)d_in[6];
  const float* be3 = (const float*)d_in[7];
  const float* Wd1 = (const float*)d_in[8];
  const float* bd1 = (const float*)d_in[9];
  const float* Wd2 = (const float*)d_in[10];
  const float* bd2 = (const float*)d_in[11];
  const float* Wd3 = (const float*)d_in[12];
  const float* bd3 = (const float*)d_in[13];
  float* out = (float*)d_out;

  char* p = (char*)d_ws;
  auto alloc = [&](size_t bytes) {
    char* r = p;
    p += (bytes + 255) & ~(size_t)255;
    return r;
  };
  ushortT* We1T = (ushortT*)alloc((size_t)H_DIM * D_DIM * 2);
  ushortT* We2T = (ushortT*)alloc((size_t)H_DIM * H_DIM * 2);
  ushortT* We3T = (ushortT*)alloc((size_t)Z_DIM * H_DIM * 2);
  ushortT* Wd1T = (ushortT*)alloc((size_t)H_DIM * Z_DIM * 2);
  ushortT* Wd2T = (ushortT*)alloc((size_t)H_DIM * H_DIM * 2);
  ushortT* Wd3T = (ushortT*)alloc((size_t)D_DIM * H_DIM * 2);
  ushortT* A_enc = (ushortT*)alloc((size_t)MENC * D_DIM * 2);
  ushortT* bufX = (ushortT*)alloc((size_t)MENC * H_DIM * 2);  // h1 / t2
  ushortT* bufY = (ushortT*)alloc((size_t)MENC * H_DIM * 2);  // h2 / A2
  ushortT* z = (ushortT*)alloc((size_t)MENC * Z_DIM * 2);
  // split-K partial buffer: max(3 planes of MENCxH f32, 8 of MENCxZ)
  float* Pbig = (float*)alloc((size_t)3 * MENC * H_DIM * 4);
  float* wbuf = (float*)alloc((size_t)NROWS * 4);

  const dim3 blk(256);
  const float* nofp = nullptr;
  const ushortT* nobf = nullptr;

  // x -> bf16, per-neighbor weights, zero loss accumulator; weights -> bf16^T
  prep_kernel<<<dim3(MENC), blk, 0, stream>>>(x_c, x_nn, A_enc, wbuf, out);
  trans_all<<<dim3(8256), blk, 0, stream>>>(We1, We2, We3, Wd1, Wd2, Wd3,
                                            We1T, We2T, We3T, Wd1T, Wd2T, Wd3T);

  // enc1: h1 = relu(A_enc @ We1 + be1). Split-K S=3 -> 792 blocks.
  gemmr<EP_PART, 128><<<dim3(8, 33, 3), blk, 0, stream>>>(
      A_enc, We1T, nofp, nullptr, Pbig, MENC, H_DIM, D_DIM, D_DIM / 3,
      nobf, nofp, nullptr);
  reduce_lin<3, 1><<<dim3((MENC * H_DIM) / 1024), blk, 0, stream>>>(
      Pbig, be1, bufX, MENC * H_DIM, H_DIM - 1);

  // enc2: h2 = relu(h1 @ We2 + be2). Split-K S=2 -> 528 blocks.
  gemmr<EP_PART, 128><<<dim3(8, 33, 2), blk, 0, stream>>>(
      bufX, We2T, nofp, nullptr, Pbig, MENC, H_DIM, H_DIM, H_DIM / 2,
      nobf, nofp, nullptr);
  reduce_lin<2, 1><<<dim3((MENC * H_DIM) / 1024), blk, 0, stream>>>(
      Pbig, be2, bufY, MENC * H_DIM, H_DIM - 1);

  // z = h2 @ We3 + be3 (N=32): split-K S=8 -> 264 blocks, 4 tiles each
  gemmr<EP_PART, 32><<<dim3(1, 33, 8), blk, 0, stream>>>(
      bufY, We3T, nofp, nullptr, Pbig, MENC, Z_DIM, H_DIM, H_DIM / 8,
      nobf, nofp, nullptr);
  reduce_lin<8, 0><<<dim3((MENC * Z_DIM) / 1024), blk, 0, stream>>>(
      Pbig, be3, z, MENC * Z_DIM, Z_DIM - 1);

  // linearized decoder with frozen center masks (exact for ReLU MLP):
  // dec L1 + fused mask1: A2 = (U1c>0)?U1:0 (neighbors), relu(U1) (centers)
  gemm_sbr<EP_MASK1, 64><<<dim3(16, 33), blk, 0, stream>>>(
      z, Wd1T, bd1, bufY, MENC, H_DIM, Z_DIM, nobf, nofp, nullptr);
  // U2 = A2 @ Wd2 + bd2 (partials, all rows). Split-K S=2.
  gemmr<EP_PART, 128><<<dim3(8, 33, 2), blk, 0, stream>>>(
      bufY, Wd2T, nofp, nullptr, Pbig, MENC, H_DIM, H_DIM, H_DIM / 2,
      nobf, nofp, nullptr);
  // t2 = (U2c>0)?U2:0 directly from partials (fused mask2; U2 never stored)
  reduce_lin_mask<2><<<dim3((NROWS * H_DIM) / 1024), blk, 0, stream>>>(
      Pbig, bd2, bufX, NROWS * H_DIM, MENC * H_DIM);
  // loss GEMM: pred = t2 @ Wd3 + bd3, fused weighted-SSE vs bf16 x_nn
  gemmr<EP_LOSS, 128><<<dim3(24, 32, 1), blk, 0, stream>>>(
      bufX, Wd3T, bd3, nullptr, nullptr, NROWS, D_DIM, H_DIM, H_DIM,
      A_enc, wbuf, out);
}

// Round 10
// 391.028 us; speedup vs baseline: 1.2675x; 1.2675x over previous
//
#include <hip/hip_runtime.h>
#include <math.h>

#define D_DIM 3072
#define H_DIM 1024
#define Z_DIM 32
#define BATCH 128
#define NNEI 32
#define NROWS (BATCH * NNEI) /* 4096 */
#define MENC (NROWS + BATCH) /* 4224 */

typedef __attribute__((ext_vector_type(8))) short short8;
typedef __attribute__((ext_vector_type(4))) float f32x4;
typedef unsigned short ushortT;

__device__ __forceinline__ unsigned short f2bf(float f) {
  union { float f; unsigned int u; } v; v.f = f;
  unsigned int r = v.u + 0x7FFFu + ((v.u >> 16) & 1u);
  return (unsigned short)(r >> 16);
}
__device__ __forceinline__ float bf2f(unsigned short b) {
  union { unsigned int u; float f; } v; v.u = ((unsigned int)b) << 16;
  return v.f;
}

// Async global->LDS, 16B per lane. LDS dest is WAVE-UNIFORM base; HW adds
// lane*16. Global src is per-lane.
__device__ __forceinline__ void gl16(const ushortT* g, ushortT* l) {
  typedef __attribute__((address_space(1))) const void gvoid;
  typedef __attribute__((address_space(3))) void lvoid;
  __builtin_amdgcn_global_load_lds((gvoid*)(const void*)g, (lvoid*)(void*)l,
                                   16, 0, 0);
}
// Inline-asm ds_read_b128 (gemm_sb only; R14 rationale).
typedef __attribute__((address_space(3))) const ushortT lds_cus;
__device__ __forceinline__ short8 ldsr(const ushortT* p) {
  short8 r;
  asm volatile("ds_read_b128 %0, %1" : "=v"(r) : "v"((lds_cus*)p));
  return r;
}
#define BAR() asm volatile("s_barrier" ::: "memory")
#define VM0() asm volatile("s_waitcnt vmcnt(0)" ::: "memory")
#define LGKM0() asm volatile("s_waitcnt lgkmcnt(0)" ::: "memory")

enum { EP_RELU = 0, EP_BIAS = 1, EP_PART = 2, EP_LOSS = 3, EP_MASK1 = 4 };

// R19: BK=128 amortized-roundtrip GEMM.
// Cross-round invariant (R11/R12/R14/R17): per-block serial cost is
// ~5.2-5.8k cyc PER BARRIER-ROUNDTRIP, independent of BK (R11's BK=64 iter
// cost the same 5150 as R12's BK=32) and of barrier count. The floor is
// the rendezvous+DMA-drain machinery, not the staged bytes. So: 4x the
// work per roundtrip (BK=128), paying the toll 4x less often. LDS 64KB ->
// 2 resident blocks (vs 3): net predicted (4x work)/(2/3 resid) ~ 2.6x.
// Structure: R12's verified single-buffer 2-barrier loop (simplest):
//   per tile: barrier; 16 gl16 (A:8, B:8@TN128); barrier (compiler emits
//   full vmcnt/lgkm drain); 4x [8 ds_read_b128 + 16 MFMA].
// LDS chunk layout: chunk = 16 rows x 32 k = 1KB at kh*4096 + c*512
// (ushorts), lane fragment lane*8. Linear in lane order (gload_lds
// constraint), conflict-free b128.
// A: MxK bf16 row-major, BT: NxK bf16. M%128==0, N%TN==0, Ks%128==0.
template <int MODE, int TN>
__global__ __launch_bounds__(256) __attribute__((amdgpu_waves_per_eu(2)))
void gemm128(
    const ushortT* __restrict__ A, const ushortT* __restrict__ BT,
    const float* __restrict__ bias, ushortT* __restrict__ C,
    float* __restrict__ P, int M, int N, int K, int Ks,
    const ushortT* __restrict__ xa,    // EP_LOSS: M x N bf16 (x_nn)
    const float* __restrict__ wrow,    // EP_LOSS: per-row weight
    float* __restrict__ out) {
  constexpr int NF = TN / 32;   // 4 (TN=128), 2 (TN=64), 1 (TN=32)

  __shared__ __align__(16) ushortT As[16384];     // 128 rows x 128 k
  __shared__ __align__(16) ushortT Bs[TN * 128];  // TN rows x 128 k

  const int t = threadIdx.x;
  const int wave = t >> 6;
  const int lane = t & 63;
  const int quad = lane >> 4;
  const int lm = lane & 15;

  // XCD-bijective swizzle (FETCH 105->42MB). Only when nwg%8==0.
  int id = blockIdx.y * gridDim.x + blockIdx.x;
  const int nwg = gridDim.x * gridDim.y;
  if ((nwg & 7) == 0) id = (id & 7) * (nwg >> 3) + (id >> 3);
  const int bm = (id / gridDim.x) * 128;
  const int bn = (id % gridDim.x) * TN;

  const int koff = blockIdx.z * Ks;
  const int wr = (wave >> 1) * 64;
  const int wc = (wave & 1) * (TN / 2);

  f32x4 acc[4][NF];
#pragma unroll
  for (int i = 0; i < 4; ++i)
#pragma unroll
    for (int j = 0; j < NF; ++j) acc[i][j] = (f32x4)0.f;

  // staging: lane l -> (row-in-16 = l&15, k-quad = (l>>4)*8).
  // A: wave w stages chunks c = {2w, 2w+1} for each kh in 0..3.
  const int srow = lane & 15;
  const int sk8 = (lane >> 4) * 8;
  const ushortT* gA =
      A + (size_t)(bm + wave * 32 + srow) * K + koff + sk8;
  const size_t row16K = (size_t)16 * K;

  const ushortT* gB;
  if (TN == 128) {
    gB = BT + (size_t)(bn + wave * 32 + srow) * K + koff + sk8;
  } else if (TN == 64) {
    gB = BT + (size_t)(bn + wave * 16 + srow) * K + koff + sk8;
  } else {  // TN == 32: waves (w&1) cover the two 16-row chunks
    gB = BT + (size_t)(bn + (wave & 1) * 16 + srow) * K + koff + sk8;
  }

#define STAGE(k0)                                                         \
  {                                                                       \
    const size_t o = (size_t)(k0) * 128;                                  \
    _Pragma("unroll")                                                     \
    for (int kh = 0; kh < 4; ++kh) {                                      \
      gl16(gA + o + kh * 32, &As[kh * 4096 + wave * 1024]);               \
      gl16(gA + row16K + o + kh * 32, &As[kh * 4096 + wave * 1024 + 512]);\
      if (TN == 128) {                                                    \
        gl16(gB + o + kh * 32, &Bs[kh * 4096 + wave * 1024]);             \
        gl16(gB + row16K + o + kh * 32,                                   \
             &Bs[kh * 4096 + wave * 1024 + 512]);                         \
      } else if (TN == 64) {                                              \
        gl16(gB + o + kh * 32, &Bs[kh * 2048 + wave * 512]);              \
      }                                                                   \
    }                                                                     \
    if (TN == 32) {                                                       \
      const int kh0 = (wave >> 1) * 2;                                    \
      gl16(gB + o + kh0 * 32, &Bs[kh0 * 1024 + (wave & 1) * 512]);        \
      gl16(gB + o + (kh0 + 1) * 32,                                       \
           &Bs[(kh0 + 1) * 1024 + (wave & 1) * 512]);                     \
    }                                                                     \
  }

  const int nk = Ks / 128;
  for (int k0 = 0; k0 < nk; ++k0) {
    __syncthreads();  // prior roundtrip's LDS readers done
    STAGE(k0);
    __syncthreads();  // full drain (vmcnt0+lgkm0) -> tile staged
#pragma unroll
    for (int kh = 0; kh < 4; ++kh) {
      const ushortT* arp = &As[kh * 4096 + (wr >> 4) * 512 + lane * 8];
      const ushortT* brp =
          &Bs[(TN == 128 ? kh * 4096 : TN == 64 ? kh * 2048 : kh * 1024) +
              (wc >> 4) * 512 + lane * 8];
      short8 af[4], bf[NF];
#pragma unroll
      for (int mt = 0; mt < 4; ++mt) af[mt] = *(const short8*)(arp + mt * 512);
#pragma unroll
      for (int nt = 0; nt < NF; ++nt) bf[nt] = *(const short8*)(brp + nt * 512);
#pragma unroll
      for (int mt = 0; mt < 4; ++mt)
#pragma unroll
        for (int nt = 0; nt < NF; ++nt)
          acc[mt][nt] = __builtin_amdgcn_mfma_f32_16x16x32_bf16(
              af[mt], bf[nt], acc[mt][nt], 0, 0, 0);
    }
  }
#undef STAGE

  // C/D layout: col = lane&15, row = quad*4 + reg
  if (MODE == EP_LOSS) {
    __shared__ float red[256];
    float lsum = 0.f;
#pragma unroll
    for (int mt = 0; mt < 4; ++mt) {
#pragma unroll
      for (int r = 0; r < 4; ++r) {
        const int row = bm + wr + mt * 16 + quad * 4 + r;
        const float w = wrow[row];
        const ushortT* xr = xa + (size_t)row * N;
        float rs = 0.f;
#pragma unroll
        for (int nt = 0; nt < NF; ++nt) {
          const int col = bn + wc + nt * 16 + lm;
          const float d = bf2f(xr[col]) - (acc[mt][nt][r] + bias[col]);
          rs = fmaf(d, d, rs);
        }
        lsum = fmaf(w, rs, lsum);
      }
    }
    __syncthreads();
    red[t] = lsum;
    __syncthreads();
    for (int st = 128; st > 0; st >>= 1) {
      if (t < st) red[t] += red[t + st];
      __syncthreads();
    }
    if (t == 0) atomicAdd(out, red[0] * (1.0f / (float)NROWS));
  } else if (MODE == EP_PART) {
#pragma unroll
    for (int mt = 0; mt < 4; ++mt)
#pragma unroll
      for (int r = 0; r < 4; ++r) {
        const int row = bm + wr + mt * 16 + quad * 4 + r;
#pragma unroll
        for (int nt = 0; nt < NF; ++nt) {
          const int col = bn + wc + nt * 16 + lm;
          P[((size_t)blockIdx.z * M + row) * N + col] = acc[mt][nt][r];
        }
      }
  } else {
#pragma unroll
    for (int mt = 0; mt < 4; ++mt)
#pragma unroll
      for (int r = 0; r < 4; ++r) {
        const int row = bm + wr + mt * 16 + quad * 4 + r;
#pragma unroll
        for (int nt = 0; nt < NF; ++nt) {
          const int col = bn + wc + nt * 16 + lm;
          float v = acc[mt][nt][r] + bias[col];
          if (MODE == EP_RELU) v = fmaxf(v, 0.f);
          C[(size_t)row * N + col] = f2bf(v);
        }
      }
  }
}

// Single K=32 tile GEMM (dec L1): gload_lds + vmcnt(0) + one compute.
// EP_MASK1 fuses the frozen-mask apply (R16): all 16 rows of an m-tile
// share ONE center row, so U1c = z_center @ Wd1 is one broadcast A-frag +
// 1 extra MFMA per (mt,nt); epilogue emits A2 = (U1c+bias>0)?bf16(U1+bias)
// :0 for neighbor blocks, relu for center blocks (bm >= NROWS).
// (R17-verified, byte-identical.)
template <int MODE, int TN>
__global__ __launch_bounds__(256) void gemm_sb(
    const ushortT* __restrict__ A, const ushortT* __restrict__ BT,
    const float* __restrict__ bias, ushortT* __restrict__ C,
    int M, int N, int K,   // K must be 32
    const ushortT* __restrict__ xa, const float* __restrict__ wrow,
    float* __restrict__ out) {
  constexpr int NF = TN / 32;
  __shared__ __align__(16) ushortT As[4096];
  __shared__ __align__(16) ushortT Bs[TN * 32];

  const int t = threadIdx.x;
  const int wave = t >> 6;
  const int lane = t & 63;
  const int quad = lane >> 4;
  const int lm = lane & 15;

  int id = blockIdx.y * gridDim.x + blockIdx.x;
  const int nwg = gridDim.x * gridDim.y;
  if ((nwg & 7) == 0) id = (id & 7) * (nwg >> 3) + (id >> 3);
  const int bm = (id / gridDim.x) * 128;
  const int bn = (id % gridDim.x) * TN;

  const int wr = (wave >> 1) * 64;
  const int wc = (wave & 1) * (TN / 2);

  const int a_r0 = (t >> 6) * 16 + (t & 15);
  const int a_q8 = ((t >> 4) & 3) * 8;
  const ushortT* ga0 = A + (size_t)(bm + a_r0) * K + a_q8;
  const ushortT* gb0 = BT + (size_t)(bn + a_r0) * K + a_q8;

  ushortT* asw = &As[wave * 512];
  ushortT* bsw = &Bs[wave * 512];
  gl16(ga0, asw);
  gl16(ga0 + (size_t)64 * K, asw + 2048);
  gl16(gb0, bsw);
  if (TN == 128) gl16(gb0 + (size_t)64 * K, bsw + 2048);
  VM0();
  BAR();

  f32x4 acc[4][NF];
#pragma unroll
  for (int i = 0; i < 4; ++i)
#pragma unroll
    for (int j = 0; j < NF; ++j) acc[i][j] = (f32x4)0.f;

  const ushortT* arp = As + (wr >> 4) * 512 + lane * 8;
  const ushortT* brp = Bs + (wc >> 4) * 512 + lane * 8;
  short8 af[4], bf[NF];
#pragma unroll
  for (int mt = 0; mt < 4; ++mt) af[mt] = ldsr(arp + mt * 512);
#pragma unroll
  for (int nt = 0; nt < NF; ++nt) bf[nt] = ldsr(brp + nt * 512);
  LGKM0();
  __builtin_amdgcn_sched_barrier(0);
#pragma unroll
  for (int mt = 0; mt < 4; ++mt)
#pragma unroll
    for (int nt = 0; nt < NF; ++nt)
      acc[mt][nt] = __builtin_amdgcn_mfma_f32_16x16x32_bf16(
          af[mt], bf[nt], acc[mt][nt], 0, 0, 0);

  // mask GEMM: U1c = z_center @ Wd1 (broadcast A-frag)
  f32x4 acc2[4][NF];
  if (MODE == EP_MASK1) {
#pragma unroll
    for (int i = 0; i < 4; ++i)
#pragma unroll
      for (int j = 0; j < NF; ++j) acc2[i][j] = (f32x4)0.f;
    if (bm < NROWS) {
      short8 az[4];
#pragma unroll
      for (int mt = 0; mt < 4; ++mt) {
        const int cz = NROWS + ((bm + wr + mt * 16) >> 5);
        az[mt] = *(const short8*)(A + (size_t)cz * K + ((lane >> 4) << 3));
      }
#pragma unroll
      for (int mt = 0; mt < 4; ++mt)
#pragma unroll
        for (int nt = 0; nt < NF; ++nt)
          acc2[mt][nt] = __builtin_amdgcn_mfma_f32_16x16x32_bf16(
              az[mt], bf[nt], acc2[mt][nt], 0, 0, 0);
    }
  }

  if (MODE == EP_MASK1) {
    const bool nb = (bm < NROWS);
#pragma unroll
    for (int mt = 0; mt < 4; ++mt)
#pragma unroll
      for (int r = 0; r < 4; ++r) {
        const int row = bm + wr + mt * 16 + quad * 4 + r;
#pragma unroll
        for (int nt = 0; nt < NF; ++nt) {
          const int col = bn + wc + nt * 16 + lm;
          const float v = acc[mt][nt][r] + bias[col];
          ushortT o;
          if (nb) {
            const float m = acc2[mt][nt][r] + bias[col];
            o = (m > 0.f) ? f2bf(v) : (ushortT)0;
          } else {
            o = f2bf(fmaxf(v, 0.f));
          }
          C[(size_t)row * N + col] = o;
        }
      }
  } else {
#pragma unroll
    for (int mt = 0; mt < 4; ++mt)
#pragma unroll
      for (int r = 0; r < 4; ++r) {
        const int row = bm + wr + mt * 16 + quad * 4 + r;
#pragma unroll
        for (int nt = 0; nt < NF; ++nt) {
          const int col = bn + wc + nt * 16 + lm;
          float v = acc[mt][nt][r] + bias[col];
          if (MODE == EP_RELU) v = fmaxf(v, 0.f);
          C[(size_t)row * N + col] = f2bf(v);
        }
      }
  }
}

// sum split-K fp32 partials + bias (+optional relu) -> bf16. N power of 2.
template <int S, int RELU>
__global__ __launch_bounds__(256) void reduce_lin(
    const float* __restrict__ P, const float* __restrict__ bias,
    ushortT* __restrict__ outp, int MN, int Nmask) {
  const int i4 = (blockIdx.x * 256 + threadIdx.x) * 4;
  if (i4 >= MN) return;
  float4 s = *(const float4*)(P + i4);
#pragma unroll
  for (int k = 1; k < S; ++k) {
    const float4 q = *(const float4*)(P + (size_t)k * MN + i4);
    s.x += q.x; s.y += q.y; s.z += q.z; s.w += q.w;
  }
  const float4 b = *(const float4*)(bias + (i4 & Nmask));
  float vx = s.x + b.x, vy = s.y + b.y, vz = s.z + b.z, vw = s.w + b.w;
  if (RELU) {
    vx = fmaxf(vx, 0.f); vy = fmaxf(vy, 0.f);
    vz = fmaxf(vz, 0.f); vw = fmaxf(vw, 0.f);
  }
  ushort4 o;
  o.x = f2bf(vx); o.y = f2bf(vy); o.z = f2bf(vz); o.w = f2bf(vw);
  *(ushort4*)(outp + i4) = o;
}

// Fused split-K reduce + frozen-mask apply for dec L2 (R16).
// t2 = (U2[center]>0) ? bf16(U2) : 0 for the NROWS neighbor rows; U2 (own
// row AND center row) re-summed from the S partial planes + bias. Center
// reads 32x-reused -> L2-hot. U2 never materialized.
template <int S>
__global__ __launch_bounds__(256) void reduce_lin_mask(
    const float* __restrict__ P, const float* __restrict__ bias,
    ushortT* __restrict__ outp, int MN /* NROWS*H */, int MNfull /* MENC*H */) {
  const int i4 = (blockIdx.x * 256 + threadIdx.x) * 4;
  if (i4 >= MN) return;
  const int r = i4 >> 10;
  const int c = i4 & 1023;
  const size_t ci = (((size_t)(NROWS + (r >> 5))) << 10) + c;
  float4 s = *(const float4*)(P + i4);
  float4 sc = *(const float4*)(P + ci);
#pragma unroll
  for (int k = 1; k < S; ++k) {
    const float4 q = *(const float4*)(P + (size_t)k * MNfull + i4);
    const float4 qc = *(const float4*)(P + (size_t)k * MNfull + ci);
    s.x += q.x; s.y += q.y; s.z += q.z; s.w += q.w;
    sc.x += qc.x; sc.y += qc.y; sc.z += qc.z; sc.w += qc.w;
  }
  const float4 b = *(const float4*)(bias + c);
  const float ux = s.x + b.x, uy = s.y + b.y, uz = s.z + b.z, uw = s.w + b.w;
  const float mx = sc.x + b.x, my = sc.y + b.y, mz = sc.z + b.z,
              mw = sc.w + b.w;
  ushort4 o;
  o.x = (mx > 0.f) ? f2bf(ux) : (ushortT)0;
  o.y = (my > 0.f) ? f2bf(uy) : (ushortT)0;
  o.z = (mz > 0.f) ? f2bf(uz) : (ushortT)0;
  o.w = (mw > 0.f) ? f2bf(uw) : (ushortT)0;
  *(ushort4*)(outp + i4) = o;
}

// Fused prep: x fp32 -> bf16 A_enc; per-(b,n) weights from dist^2; zero out[0].
__global__ __launch_bounds__(256) void prep_kernel(
    const float* __restrict__ x_c, const float* __restrict__ x_nn,
    ushortT* __restrict__ A_enc, float* __restrict__ wbuf, float* __restrict__ out) {
  const int i = blockIdx.x;
  const int t = threadIdx.x;
  if (i < NROWS) {
    const float* src = x_nn + (size_t)i * D_DIM;
    const float* ctr = x_c + (size_t)(i >> 5) * D_DIM;
    ushortT* dst = A_enc + (size_t)i * D_DIM;
    float s = 0.f;
    for (int d = t * 4; d < D_DIM; d += 1024) {
      const float4 v = *(const float4*)(src + d);
      const float4 c = *(const float4*)(ctr + d);
      ushort4 o;
      o.x = f2bf(v.x); o.y = f2bf(v.y); o.z = f2bf(v.z); o.w = f2bf(v.w);
      *(ushort4*)(dst + d) = o;
      const float dx = v.x - c.x, dy = v.y - c.y, dz = v.z - c.z, dw = v.w - c.w;
      s += dx * dx + dy * dy + dz * dz + dw * dw;
    }
    __shared__ float red[256];
    red[t] = s;
    __syncthreads();
    for (int st = 128; st > 0; st >>= 1) {
      if (t < st) red[t] += red[t + st];
      __syncthreads();
    }
    if (t == 0) {
      wbuf[i] = (red[0] > 1e-24f) ? 1.0f : 0.5f;
      if (i == 0) out[0] = 0.f;
    }
  } else {
    const int r = i - NROWS;
    const float* src = x_c + (size_t)r * D_DIM;
    ushortT* dst = A_enc + (size_t)i * D_DIM;
    for (int d = t * 4; d < D_DIM; d += 1024) {
      const float4 v = *(const float4*)(src + d);
      ushort4 o;
      o.x = f2bf(v.x); o.y = f2bf(v.y); o.z = f2bf(v.z); o.w = f2bf(v.w);
      *(ushort4*)(dst + d) = o;
    }
  }
}

// Batched transpose+cast of all six weights: W (KxN f32) -> WT (NxK bf16).
// Coalesced write phase: thread -> (n = tid>>3, kq = tid&7), each emits a
// ushort4 => 32-thread n-rows write 256B contiguous.
__global__ __launch_bounds__(256) void trans_all(
    const float* __restrict__ We1, const float* __restrict__ We2,
    const float* __restrict__ We3, const float* __restrict__ Wd1,
    const float* __restrict__ Wd2, const float* __restrict__ Wd3,
    ushortT* __restrict__ We1T, ushortT* __restrict__ We2T,
    ushortT* __restrict__ We3T, ushortT* __restrict__ Wd1T,
    ushortT* __restrict__ Wd2T, ushortT* __restrict__ Wd3T) {
  const int b = blockIdx.x;
  const float* W; ushortT* WT; int K, N, loc;
  if (b < 3072)      { W = We1; WT = We1T; K = 3072; N = 1024; loc = b; }
  else if (b < 4096) { W = We2; WT = We2T; K = 1024; N = 1024; loc = b - 3072; }
  else if (b < 4128) { W = We3; WT = We3T; K = 1024; N = 32;   loc = b - 4096; }
  else if (b < 4160) { W = Wd1; WT = Wd1T; K = 32;   N = 1024; loc = b - 4128; }
  else if (b < 5184) { W = Wd2; WT = Wd2T; K = 1024; N = 1024; loc = b - 4160; }
  else               { W = Wd3; WT = Wd3T; K = 1024; N = 3072; loc = b - 5184; }
  const int ntiles = N >> 5;
  const int n0 = (loc % ntiles) * 32;
  const int k0 = (loc / ntiles) * 32;
  __shared__ float tile[32][33];
  const int tx = threadIdx.x & 31;
  const int ty = threadIdx.x >> 5;
  for (int i = ty; i < 32; i += 8)
    tile[i][tx] = W[(size_t)(k0 + i) * N + n0 + tx];
  __syncthreads();
  const int n = threadIdx.x >> 3;
  const int kq = (threadIdx.x & 7) * 4;
  ushort4 o;
  o.x = f2bf(tile[kq + 0][n]);
  o.y = f2bf(tile[kq + 1][n]);
  o.z = f2bf(tile[kq + 2][n]);
  o.w = f2bf(tile[kq + 3][n]);
  *(ushort4*)(WT + (size_t)(n0 + n) * K + k0 + kq) = o;
}

extern "C" void kernel_launch(void* const* d_in, const int* in_sizes, int n_in,
                              void* d_out, int out_size, void* d_ws, size_t ws_size,
                              hipStream_t stream) {
  const float* x_c = (const float*)d_in[0];
  const float* x_nn = (const float*)d_in[1];
  const float* We1 = (const float*)d_in[2];
  const float* be1 = (const float*)d_in[3];
  const float* We2 = (const float*)d_in[4];
  const float* be2 = (const float*)d_in[5];
  const float* We3 = (const float*)d_in[6];
  const float* be3 = (const float*)d_in[7];
  const float* Wd1 = (const float*)d_in[8];
  const float* bd1 = (const float*)d_in[9];
  const float* Wd2 = (const float*)d_in[10];
  const float* bd2 = (const float*)d_in[11];
  const float* Wd3 = (const float*)d_in[12];
  const float* bd3 = (const float*)d_in[13];
  float* out = (float*)d_out;

  char* p = (char*)d_ws;
  auto alloc = [&](size_t bytes) {
    char* r = p;
    p += (bytes + 255) & ~(size_t)255;
    return r;
  };
  ushortT* We1T = (ushortT*)alloc((size_t)H_DIM * D_DIM * 2);
  ushortT* We2T = (ushortT*)alloc((size_t)H_DIM * H_DIM * 2);
  ushortT* We3T = (ushortT*)alloc((size_t)Z_DIM * H_DIM * 2);
  ushortT* Wd1T = (ushortT*)alloc((size_t)H_DIM * Z_DIM * 2);
  ushortT* Wd2T = (ushortT*)alloc((size_t)H_DIM * H_DIM * 2);
  ushortT* Wd3T = (ushortT*)alloc((size_t)D_DIM * H_DIM * 2);
  ushortT* A_enc = (ushortT*)alloc((size_t)MENC * D_DIM * 2);
  ushortT* bufX = (ushortT*)alloc((size_t)MENC * H_DIM * 2);  // h1 / t2
  ushortT* bufY = (ushortT*)alloc((size_t)MENC * H_DIM * 2);  // h2 / A2
  ushortT* z = (ushortT*)alloc((size_t)MENC * Z_DIM * 2);
  // split-K partial buffer: max(3 planes of MENCxH f32, 8 of MENCxZ)
  float* Pbig = (float*)alloc((size_t)3 * MENC * H_DIM * 4);
  float* wbuf = (float*)alloc((size_t)NROWS * 4);

  const dim3 blk(256);
  const float* nofp = nullptr;
  const ushortT* nobf = nullptr;

  // x -> bf16, per-neighbor weights, zero loss accumulator; weights -> bf16^T
  prep_kernel<<<dim3(MENC), blk, 0, stream>>>(x_c, x_nn, A_enc, wbuf, out);
  trans_all<<<dim3(8256), blk, 0, stream>>>(We1, We2, We3, Wd1, Wd2, Wd3,
                                            We1T, We2T, We3T, Wd1T, Wd2T, Wd3T);

  // enc1: h1 = relu(A_enc @ We1 + be1). Split-K S=3, Ks=1024, nk=8.
  gemm128<EP_PART, 128><<<dim3(8, 33, 3), blk, 0, stream>>>(
      A_enc, We1T, nofp, nullptr, Pbig, MENC, H_DIM, D_DIM, D_DIM / 3,
      nobf, nofp, nullptr);
  reduce_lin<3, 1><<<dim3((MENC * H_DIM) / 1024), blk, 0, stream>>>(
      Pbig, be1, bufX, MENC * H_DIM, H_DIM - 1);

  // enc2: h2 = relu(h1 @ We2 + be2). Split-K S=2, Ks=512, nk=4.
  gemm128<EP_PART, 128><<<dim3(8, 33, 2), blk, 0, stream>>>(
      bufX, We2T, nofp, nullptr, Pbig, MENC, H_DIM, H_DIM, H_DIM / 2,
      nobf, nofp, nullptr);
  reduce_lin<2, 1><<<dim3((MENC * H_DIM) / 1024), blk, 0, stream>>>(
      Pbig, be2, bufY, MENC * H_DIM, H_DIM - 1);

  // z = h2 @ We3 + be3 (N=32): split-K S=8, Ks=128, nk=1.
  gemm128<EP_PART, 32><<<dim3(1, 33, 8), blk, 0, stream>>>(
      bufY, We3T, nofp, nullptr, Pbig, MENC, Z_DIM, H_DIM, H_DIM / 8,
      nobf, nofp, nullptr);
  reduce_lin<8, 0><<<dim3((MENC * Z_DIM) / 1024), blk, 0, stream>>>(
      Pbig, be3, z, MENC * Z_DIM, Z_DIM - 1);

  // linearized decoder with frozen center masks (exact for ReLU MLP):
  // dec L1 + fused mask1: A2 = (U1c>0)?U1:0 (neighbors), relu(U1) (centers)
  gemm_sb<EP_MASK1, 64><<<dim3(16, 33), blk, 0, stream>>>(
      z, Wd1T, bd1, bufY, MENC, H_DIM, Z_DIM, nobf, nofp, nullptr);
  // U2 = A2 @ Wd2 + bd2 (partials, all rows). Split-K S=2, Ks=512, nk=4.
  gemm128<EP_PART, 128><<<dim3(8, 33, 2), blk, 0, stream>>>(
      bufY, Wd2T, nofp, nullptr, Pbig, MENC, H_DIM, H_DIM, H_DIM / 2,
      nobf, nofp, nullptr);
  // t2 = (U2c>0)?U2:0 directly from partials (fused mask2; U2 never stored)
  reduce_lin_mask<2><<<dim3((NROWS * H_DIM) / 1024), blk, 0, stream>>>(
      Pbig, bd2, bufX, NROWS * H_DIM, MENC * H_DIM);
  // loss GEMM: pred = t2 @ Wd3 + bd3, fused weighted-SSE vs bf16 x_nn
  // (768 blocks, nk=8)
  gemm128<EP_LOSS, 128><<<dim3(24, 32, 1), blk, 0, stream>>>(
      bufX, Wd3T, bd3, nullptr, nullptr, NROWS, D_DIM, H_DIM, H_DIM,
      A_enc, wbuf, out);
}

// Round 11
// 354.946 us; speedup vs baseline: 1.3964x; 1.1017x over previous
//
#include <hip/hip_runtime.h>
#include <math.h>

#define D_DIM 3072
#define H_DIM 1024
#define Z_DIM 32
#define BATCH 128
#define NNEI 32
#define NROWS (BATCH * NNEI) /* 4096 */
#define MENC (NROWS + BATCH) /* 4224 */

typedef __attribute__((ext_vector_type(8))) short short8;
typedef __attribute__((ext_vector_type(4))) float f32x4;
typedef unsigned short ushortT;

__device__ __forceinline__ unsigned short f2bf(float f) {
  union { float f; unsigned int u; } v; v.f = f;
  unsigned int r = v.u + 0x7FFFu + ((v.u >> 16) & 1u);
  return (unsigned short)(r >> 16);
}
__device__ __forceinline__ float bf2f(unsigned short b) {
  union { unsigned int u; float f; } v; v.u = ((unsigned int)b) << 16;
  return v.f;
}

// Async global->LDS, 16B per lane. LDS dest is WAVE-UNIFORM base; HW adds
// lane*16. Global src is per-lane.
__device__ __forceinline__ void gl16(const ushortT* g, ushortT* l) {
  typedef __attribute__((address_space(1))) const void gvoid;
  typedef __attribute__((address_space(3))) void lvoid;
  __builtin_amdgcn_global_load_lds((gvoid*)(const void*)g, (lvoid*)(void*)l,
                                   16, 0, 0);
}
// Inline-asm ds_read_b128: invisible to SIInsertWaitcnts (avoids the
// conservative vmcnt(0) drain vs outstanding LDS-DMA; R14). Completion is
// OUR job: s_waitcnt lgkmcnt(0) + sched_barrier(0) before MFMAs (rule 18).
typedef __attribute__((address_space(3))) const ushortT lds_cus;
__device__ __forceinline__ short8 ldsr(const ushortT* p) {
  short8 r;
  asm volatile("ds_read_b128 %0, %1" : "=v"(r) : "v"((lds_cus*)p));
  return r;
}
#define BAR() asm volatile("s_barrier" ::: "memory")
#define VM0() asm volatile("s_waitcnt vmcnt(0)" ::: "memory")
#define LGKM0() asm volatile("s_waitcnt lgkmcnt(0)" ::: "memory")

template <int N>
__device__ __forceinline__ void vmw() {
  if constexpr (N == 0)      asm volatile("s_waitcnt vmcnt(0)" ::: "memory");
  else if constexpr (N == 2) asm volatile("s_waitcnt vmcnt(2)" ::: "memory");
  else if constexpr (N == 3) asm volatile("s_waitcnt vmcnt(3)" ::: "memory");
  else if constexpr (N == 4) asm volatile("s_waitcnt vmcnt(4)" ::: "memory");
}

enum { EP_RELU = 0, EP_BIAS = 1, EP_PART = 2, EP_LOSS = 3, EP_MASK1 = 4 };

// R14/R17 ring-3 pipelined GEMM -- the session's verified-best core
// (359.0 us total), kept byte-identical.
// R19 post-mortem closed the structural search: per-CU staging throughput
// is pinned at ~9 B/cyc (~1700-1900 cyc per 16KB tile-step) regardless of
// BK (32/64/128), sync scheme (7 variants), or streams>3. All GEMM-core
// axes tested; family plateau for this 264-tile problem shape.
// BM=128, BK=32, LDS ring of 3 tile-slots (48KB @TN=128), gl16 staging,
// 2-tile lookahead, ONE barrier per tile, counted vmcnt, asm ds_read.
// A: MxK bf16 row-major, BT: NxK bf16. M%128==0, N%TN==0, Ks%32==0, nk>=2.
template <int MODE, int TN>
__global__ __launch_bounds__(256) __attribute__((amdgpu_waves_per_eu(3)))
void gemm32(
    const ushortT* __restrict__ A, const ushortT* __restrict__ BT,
    const float* __restrict__ bias, ushortT* __restrict__ C,
    float* __restrict__ P, int M, int N, int K, int Ks,
    const ushortT* __restrict__ xa,    // EP_LOSS: M x N bf16 (x_nn)
    const float* __restrict__ wrow,    // EP_LOSS: per-row weight
    float* __restrict__ out) {
  constexpr int NF = TN / 32;   // 4 (TN=128), 2 (TN=64), 1 (TN=32)

  __shared__ __align__(16) ushortT As[3][4096];     // 3 x (128 x 32)
  __shared__ __align__(16) ushortT Bs[3][TN * 32];

  const int t = threadIdx.x;
  const int wave = t >> 6;
  const int lane = t & 63;
  const int quad = lane >> 4;
  const int lm = lane & 15;

  // XCD-bijective swizzle (FETCH 105->42MB). Only when nwg%8==0.
  int id = blockIdx.y * gridDim.x + blockIdx.x;
  const int nwg = gridDim.x * gridDim.y;
  if ((nwg & 7) == 0) id = (id & 7) * (nwg >> 3) + (id >> 3);
  const int bm = (id / gridDim.x) * 128;
  const int bn = (id % gridDim.x) * TN;

  const int koff = blockIdx.z * Ks;
  const int wr = (wave >> 1) * 64;
  const int wc = (wave & 1) * (TN / 2);

  f32x4 acc[4][NF];
#pragma unroll
  for (int i = 0; i < 4; ++i)
#pragma unroll
    for (int j = 0; j < NF; ++j) acc[i][j] = (f32x4)0.f;

  // staging: lane l -> (row = l&15, kq = l>>4); wave w owns chunks {2w,2w+1}
  const int srow = lane & 15;
  const int skq = lane >> 4;
  const ushortT* gA =
      A + (size_t)(bm + wave * 32 + srow) * K + koff + skq * 8;
  const size_t row16 = (size_t)16 * K;

  const ushortT* gB;
  if (TN == 128) {
    gB = BT + (size_t)(bn + wave * 32 + srow) * K + koff + skq * 8;
  } else if (TN == 64) {
    gB = BT + (size_t)(bn + wave * 16 + srow) * K + koff + skq * 8;
  } else {  // TN == 32: only waves 0,1 stage B (one chunk each)
    gB = BT + (size_t)(bn + (wave & 1) * 16 + srow) * K + koff + skq * 8;
  }

#define STAGE(kk, sl)                                           \
  {                                                             \
    const size_t o = (size_t)(kk) * 32;                         \
    ushortT* lA = &As[sl][wave * 1024];                         \
    gl16(gA + o, lA);                                           \
    gl16(gA + row16 + o, lA + 512);                             \
    if (TN == 128) {                                            \
      ushortT* lB = &Bs[sl][wave * 1024];                       \
      gl16(gB + o, lB);                                         \
      gl16(gB + row16 + o, lB + 512);                           \
    } else if (TN == 64) {                                      \
      gl16(gB + o, &Bs[sl][wave * 512]);                        \
    } else {                                                    \
      if (wave < 2) gl16(gB + o, &Bs[sl][(wave & 1) * 512]);    \
    }                                                           \
  }

  const int nk = Ks / 32;
  // prologue: 2-deep prefetch into slots 0,1
  STAGE(0, 0);
  if (nk > 1) STAGE(1, 1);

  int sl = 0;          // slot holding current tile
  int sn = 2;          // slot to stage (t0+2) into
  for (int t0 = 0; t0 < nk; ++t0) {
    // retire tile t0's DMAs: only tile-(t0+1)'s NLD loads may remain
    if (t0 + 1 < nk) {
      if (TN == 128) vmw<4>();
      else if (TN == 64) vmw<3>();
      else { if (wave < 2) vmw<3>(); else vmw<2>(); }
    } else {
      vmw<0>();
    }
    BAR();  // everyone's tile-t0 loads landed; slot sn free
    if (t0 + 2 < nk) STAGE(t0 + 2, sn);

    const ushortT* arp = &As[sl][(wr >> 4) * 512 + lane * 8];
    const ushortT* brp = &Bs[sl][(wc >> 4) * 512 + lane * 8];
    short8 af[4], bf[NF];
#pragma unroll
    for (int mt = 0; mt < 4; ++mt) af[mt] = ldsr(arp + mt * 512);
#pragma unroll
    for (int nt = 0; nt < NF; ++nt) bf[nt] = ldsr(brp + nt * 512);
    LGKM0();
    __builtin_amdgcn_sched_barrier(0);
#pragma unroll
    for (int mt = 0; mt < 4; ++mt)
#pragma unroll
      for (int nt = 0; nt < NF; ++nt)
        acc[mt][nt] = __builtin_amdgcn_mfma_f32_16x16x32_bf16(
            af[mt], bf[nt], acc[mt][nt], 0, 0, 0);

    sl = (sl == 2) ? 0 : sl + 1;
    sn = (sn == 2) ? 0 : sn + 1;
  }
#undef STAGE

  // C/D layout: col = lane&15, row = quad*4 + reg
  if (MODE == EP_LOSS) {
    __shared__ float red[256];
    float lsum = 0.f;
#pragma unroll
    for (int mt = 0; mt < 4; ++mt) {
#pragma unroll
      for (int r = 0; r < 4; ++r) {
        const int row = bm + wr + mt * 16 + quad * 4 + r;
        const float w = wrow[row];
        const ushortT* xr = xa + (size_t)row * N;
        float rs = 0.f;
#pragma unroll
        for (int nt = 0; nt < NF; ++nt) {
          const int col = bn + wc + nt * 16 + lm;
          const float d = bf2f(xr[col]) - (acc[mt][nt][r] + bias[col]);
          rs = fmaf(d, d, rs);
        }
        lsum = fmaf(w, rs, lsum);
      }
    }
    __syncthreads();
    red[t] = lsum;
    __syncthreads();
    for (int st = 128; st > 0; st >>= 1) {
      if (t < st) red[t] += red[t + st];
      __syncthreads();
    }
    if (t == 0) atomicAdd(out, red[0] * (1.0f / (float)NROWS));
  } else if (MODE == EP_PART) {
#pragma unroll
    for (int mt = 0; mt < 4; ++mt)
#pragma unroll
      for (int r = 0; r < 4; ++r) {
        const int row = bm + wr + mt * 16 + quad * 4 + r;
#pragma unroll
        for (int nt = 0; nt < NF; ++nt) {
          const int col = bn + wc + nt * 16 + lm;
          P[((size_t)blockIdx.z * M + row) * N + col] = acc[mt][nt][r];
        }
      }
  } else {
#pragma unroll
    for (int mt = 0; mt < 4; ++mt)
#pragma unroll
      for (int r = 0; r < 4; ++r) {
        const int row = bm + wr + mt * 16 + quad * 4 + r;
#pragma unroll
        for (int nt = 0; nt < NF; ++nt) {
          const int col = bn + wc + nt * 16 + lm;
          float v = acc[mt][nt][r] + bias[col];
          if (MODE == EP_RELU) v = fmaxf(v, 0.f);
          C[(size_t)row * N + col] = f2bf(v);
        }
      }
  }
}

// Single K=32 tile GEMM (dec L1): gload_lds + vmcnt(0) + one compute.
// EP_MASK1 fuses the frozen-mask apply (R16): all 16 rows of an m-tile
// share ONE center row, so U1c = z_center @ Wd1 is one broadcast A-frag +
// 1 extra MFMA per (mt,nt); epilogue emits A2 = (U1c+bias>0)?bf16(U1+bias)
// :0 for neighbor blocks, relu for center blocks (bm >= NROWS).
template <int MODE, int TN>
__global__ __launch_bounds__(256) void gemm_sb(
    const ushortT* __restrict__ A, const ushortT* __restrict__ BT,
    const float* __restrict__ bias, ushortT* __restrict__ C,
    int M, int N, int K,   // K must be 32
    const ushortT* __restrict__ xa, const float* __restrict__ wrow,
    float* __restrict__ out) {
  constexpr int NF = TN / 32;
  __shared__ __align__(16) ushortT As[4096];
  __shared__ __align__(16) ushortT Bs[TN * 32];

  const int t = threadIdx.x;
  const int wave = t >> 6;
  const int lane = t & 63;
  const int quad = lane >> 4;
  const int lm = lane & 15;

  int id = blockIdx.y * gridDim.x + blockIdx.x;
  const int nwg = gridDim.x * gridDim.y;
  if ((nwg & 7) == 0) id = (id & 7) * (nwg >> 3) + (id >> 3);
  const int bm = (id / gridDim.x) * 128;
  const int bn = (id % gridDim.x) * TN;

  const int wr = (wave >> 1) * 64;
  const int wc = (wave & 1) * (TN / 2);

  const int a_r0 = (t >> 6) * 16 + (t & 15);
  const int a_q8 = ((t >> 4) & 3) * 8;
  const ushortT* ga0 = A + (size_t)(bm + a_r0) * K + a_q8;
  const ushortT* gb0 = BT + (size_t)(bn + a_r0) * K + a_q8;

  ushortT* asw = &As[wave * 512];
  ushortT* bsw = &Bs[wave * 512];
  gl16(ga0, asw);
  gl16(ga0 + (size_t)64 * K, asw + 2048);
  gl16(gb0, bsw);
  if (TN == 128) gl16(gb0 + (size_t)64 * K, bsw + 2048);
  VM0();
  BAR();

  f32x4 acc[4][NF];
#pragma unroll
  for (int i = 0; i < 4; ++i)
#pragma unroll
    for (int j = 0; j < NF; ++j) acc[i][j] = (f32x4)0.f;

  const ushortT* arp = As + (wr >> 4) * 512 + lane * 8;
  const ushortT* brp = Bs + (wc >> 4) * 512 + lane * 8;
  short8 af[4], bf[NF];
#pragma unroll
  for (int mt = 0; mt < 4; ++mt) af[mt] = ldsr(arp + mt * 512);
#pragma unroll
  for (int nt = 0; nt < NF; ++nt) bf[nt] = ldsr(brp + nt * 512);
  LGKM0();
  __builtin_amdgcn_sched_barrier(0);
#pragma unroll
  for (int mt = 0; mt < 4; ++mt)
#pragma unroll
    for (int nt = 0; nt < NF; ++nt)
      acc[mt][nt] = __builtin_amdgcn_mfma_f32_16x16x32_bf16(
          af[mt], bf[nt], acc[mt][nt], 0, 0, 0);

  // mask GEMM: U1c = z_center @ Wd1 (broadcast A-frag)
  f32x4 acc2[4][NF];
  if (MODE == EP_MASK1) {
#pragma unroll
    for (int i = 0; i < 4; ++i)
#pragma unroll
      for (int j = 0; j < NF; ++j) acc2[i][j] = (f32x4)0.f;
    if (bm < NROWS) {
      short8 az[4];
#pragma unroll
      for (int mt = 0; mt < 4; ++mt) {
        const int cz = NROWS + ((bm + wr + mt * 16) >> 5);
        az[mt] = *(const short8*)(A + (size_t)cz * K + ((lane >> 4) << 3));
      }
#pragma unroll
      for (int mt = 0; mt < 4; ++mt)
#pragma unroll
        for (int nt = 0; nt < NF; ++nt)
          acc2[mt][nt] = __builtin_amdgcn_mfma_f32_16x16x32_bf16(
              az[mt], bf[nt], acc2[mt][nt], 0, 0, 0);
    }
  }

  if (MODE == EP_MASK1) {
    const bool nb = (bm < NROWS);
#pragma unroll
    for (int mt = 0; mt < 4; ++mt)
#pragma unroll
      for (int r = 0; r < 4; ++r) {
        const int row = bm + wr + mt * 16 + quad * 4 + r;
#pragma unroll
        for (int nt = 0; nt < NF; ++nt) {
          const int col = bn + wc + nt * 16 + lm;
          const float v = acc[mt][nt][r] + bias[col];
          ushortT o;
          if (nb) {
            const float m = acc2[mt][nt][r] + bias[col];
            o = (m > 0.f) ? f2bf(v) : (ushortT)0;
          } else {
            o = f2bf(fmaxf(v, 0.f));
          }
          C[(size_t)row * N + col] = o;
        }
      }
  } else {
#pragma unroll
    for (int mt = 0; mt < 4; ++mt)
#pragma unroll
      for (int r = 0; r < 4; ++r) {
        const int row = bm + wr + mt * 16 + quad * 4 + r;
#pragma unroll
        for (int nt = 0; nt < NF; ++nt) {
          const int col = bn + wc + nt * 16 + lm;
          float v = acc[mt][nt][r] + bias[col];
          if (MODE == EP_RELU) v = fmaxf(v, 0.f);
          C[(size_t)row * N + col] = f2bf(v);
        }
      }
  }
}

// sum split-K fp32 partials + bias (+optional relu) -> bf16. N power of 2.
template <int S, int RELU>
__global__ __launch_bounds__(256) void reduce_lin(
    const float* __restrict__ P, const float* __restrict__ bias,
    ushortT* __restrict__ outp, int MN, int Nmask) {
  const int i4 = (blockIdx.x * 256 + threadIdx.x) * 4;
  if (i4 >= MN) return;
  float4 s = *(const float4*)(P + i4);
#pragma unroll
  for (int k = 1; k < S; ++k) {
    const float4 q = *(const float4*)(P + (size_t)k * MN + i4);
    s.x += q.x; s.y += q.y; s.z += q.z; s.w += q.w;
  }
  const float4 b = *(const float4*)(bias + (i4 & Nmask));
  float vx = s.x + b.x, vy = s.y + b.y, vz = s.z + b.z, vw = s.w + b.w;
  if (RELU) {
    vx = fmaxf(vx, 0.f); vy = fmaxf(vy, 0.f);
    vz = fmaxf(vz, 0.f); vw = fmaxf(vw, 0.f);
  }
  ushort4 o;
  o.x = f2bf(vx); o.y = f2bf(vy); o.z = f2bf(vz); o.w = f2bf(vw);
  *(ushort4*)(outp + i4) = o;
}

// Fused split-K reduce + frozen-mask apply for dec L2 (R16).
// t2 = (U2[center]>0) ? bf16(U2) : 0 for the NROWS neighbor rows; U2 (own
// row AND center row) re-summed from the S partial planes + bias. Center
// reads 32x-reused -> L2-hot. U2 never materialized.
template <int S>
__global__ __launch_bounds__(256) void reduce_lin_mask(
    const float* __restrict__ P, const float* __restrict__ bias,
    ushortT* __restrict__ outp, int MN /* NROWS*H */, int MNfull /* MENC*H */) {
  const int i4 = (blockIdx.x * 256 + threadIdx.x) * 4;
  if (i4 >= MN) return;
  const int r = i4 >> 10;
  const int c = i4 & 1023;
  const size_t ci = (((size_t)(NROWS + (r >> 5))) << 10) + c;
  float4 s = *(const float4*)(P + i4);
  float4 sc = *(const float4*)(P + ci);
#pragma unroll
  for (int k = 1; k < S; ++k) {
    const float4 q = *(const float4*)(P + (size_t)k * MNfull + i4);
    const float4 qc = *(const float4*)(P + (size_t)k * MNfull + ci);
    s.x += q.x; s.y += q.y; s.z += q.z; s.w += q.w;
    sc.x += qc.x; sc.y += qc.y; sc.z += qc.z; sc.w += qc.w;
  }
  const float4 b = *(const float4*)(bias + c);
  const float ux = s.x + b.x, uy = s.y + b.y, uz = s.z + b.z, uw = s.w + b.w;
  const float mx = sc.x + b.x, my = sc.y + b.y, mz = sc.z + b.z,
              mw = sc.w + b.w;
  ushort4 o;
  o.x = (mx > 0.f) ? f2bf(ux) : (ushortT)0;
  o.y = (my > 0.f) ? f2bf(uy) : (ushortT)0;
  o.z = (mz > 0.f) ? f2bf(uz) : (ushortT)0;
  o.w = (mw > 0.f) ? f2bf(uw) : (ushortT)0;
  *(ushort4*)(outp + i4) = o;
}

// R20: merged prep + weight-transpose in ONE launch (independent work;
// saves a dispatch gap and overlaps the two memory-bound phases' tails).
// Blocks [0, MENC): prep -- x fp32 -> bf16 A_enc; per-(b,n) weights from
//   dist^2; zero out[0].
// Blocks [MENC, MENC+8256): trans -- W (KxN f32) -> WT (NxK bf16), 32x32
//   tiles via LDS, coalesced ushort4 writes.
__global__ __launch_bounds__(256) void prep_trans(
    const float* __restrict__ x_c, const float* __restrict__ x_nn,
    ushortT* __restrict__ A_enc, float* __restrict__ wbuf,
    float* __restrict__ out,
    const float* __restrict__ We1, const float* __restrict__ We2,
    const float* __restrict__ We3, const float* __restrict__ Wd1,
    const float* __restrict__ Wd2, const float* __restrict__ Wd3,
    ushortT* __restrict__ We1T, ushortT* __restrict__ We2T,
    ushortT* __restrict__ We3T, ushortT* __restrict__ Wd1T,
    ushortT* __restrict__ Wd2T, ushortT* __restrict__ Wd3T) {
  const int blk = blockIdx.x;
  const int t = threadIdx.x;

  if (blk < MENC) {
    // ---- prep ----
    const int i = blk;
    if (i < NROWS) {
      const float* src = x_nn + (size_t)i * D_DIM;
      const float* ctr = x_c + (size_t)(i >> 5) * D_DIM;
      ushortT* dst = A_enc + (size_t)i * D_DIM;
      float s = 0.f;
      for (int d = t * 4; d < D_DIM; d += 1024) {
        const float4 v = *(const float4*)(src + d);
        const float4 c = *(const float4*)(ctr + d);
        ushort4 o;
        o.x = f2bf(v.x); o.y = f2bf(v.y); o.z = f2bf(v.z); o.w = f2bf(v.w);
        *(ushort4*)(dst + d) = o;
        const float dx = v.x - c.x, dy = v.y - c.y, dz = v.z - c.z,
                    dw = v.w - c.w;
        s += dx * dx + dy * dy + dz * dz + dw * dw;
      }
      __shared__ float red[256];
      red[t] = s;
      __syncthreads();
      for (int st = 128; st > 0; st >>= 1) {
        if (t < st) red[t] += red[t + st];
        __syncthreads();
      }
      if (t == 0) {
        wbuf[i] = (red[0] > 1e-24f) ? 1.0f : 0.5f;
        if (i == 0) out[0] = 0.f;
      }
    } else {
      const int r = i - NROWS;
      const float* src = x_c + (size_t)r * D_DIM;
      ushortT* dst = A_enc + (size_t)i * D_DIM;
      for (int d = t * 4; d < D_DIM; d += 1024) {
        const float4 v = *(const float4*)(src + d);
        ushort4 o;
        o.x = f2bf(v.x); o.y = f2bf(v.y); o.z = f2bf(v.z); o.w = f2bf(v.w);
        *(ushort4*)(dst + d) = o;
      }
    }
  } else {
    // ---- trans ----
    const int b = blk - MENC;
    const float* W; ushortT* WT; int K, N, loc;
    if (b < 3072)      { W = We1; WT = We1T; K = 3072; N = 1024; loc = b; }
    else if (b < 4096) { W = We2; WT = We2T; K = 1024; N = 1024; loc = b - 3072; }
    else if (b < 4128) { W = We3; WT = We3T; K = 1024; N = 32;   loc = b - 4096; }
    else if (b < 4160) { W = Wd1; WT = Wd1T; K = 32;   N = 1024; loc = b - 4128; }
    else if (b < 5184) { W = Wd2; WT = Wd2T; K = 1024; N = 1024; loc = b - 4160; }
    else               { W = Wd3; WT = Wd3T; K = 1024; N = 3072; loc = b - 5184; }
    const int ntiles = N >> 5;
    const int n0 = (loc % ntiles) * 32;
    const int k0 = (loc / ntiles) * 32;
    __shared__ float tile[32][33];
    const int tx = t & 31;
    const int ty = t >> 5;
    for (int i = ty; i < 32; i += 8)
      tile[i][tx] = W[(size_t)(k0 + i) * N + n0 + tx];
    __syncthreads();
    const int n = t >> 3;
    const int kq = (t & 7) * 4;
    ushort4 o;
    o.x = f2bf(tile[kq + 0][n]);
    o.y = f2bf(tile[kq + 1][n]);
    o.z = f2bf(tile[kq + 2][n]);
    o.w = f2bf(tile[kq + 3][n]);
    *(ushort4*)(WT + (size_t)(n0 + n) * K + k0 + kq) = o;
  }
}

extern "C" void kernel_launch(void* const* d_in, const int* in_sizes, int n_in,
                              void* d_out, int out_size, void* d_ws, size_t ws_size,
                              hipStream_t stream) {
  const float* x_c = (const float*)d_in[0];
  const float* x_nn = (const float*)d_in[1];
  const float* We1 = (const float*)d_in[2];
  const float* be1 = (const float*)d_in[3];
  const float* We2 = (const float*)d_in[4];
  const float* be2 = (const float*)d_in[5];
  const float* We3 = (const float*)d_in[6];
  const float* be3 = (const float*)d_in[7];
  const float* Wd1 = (const float*)d_in[8];
  const float* bd1 = (const float*)d_in[9];
  const float* Wd2 = (const float*)d_in[10];
  const float* bd2 = (const float*)d_in[11];
  const float* Wd3 = (const float*)d_in[12];
  const float* bd3 = (const float*)d_in[13];
  float* out = (float*)d_out;

  char* p = (char*)d_ws;
  auto alloc = [&](size_t bytes) {
    char* r = p;
    p += (bytes + 255) & ~(size_t)255;
    return r;
  };
  ushortT* We1T = (ushortT*)alloc((size_t)H_DIM * D_DIM * 2);
  ushortT* We2T = (ushortT*)alloc((size_t)H_DIM * H_DIM * 2);
  ushortT* We3T = (ushortT*)alloc((size_t)Z_DIM * H_DIM * 2);
  ushortT* Wd1T = (ushortT*)alloc((size_t)H_DIM * Z_DIM * 2);
  ushortT* Wd2T = (ushortT*)alloc((size_t)H_DIM * H_DIM * 2);
  ushortT* Wd3T = (ushortT*)alloc((size_t)D_DIM * H_DIM * 2);
  ushortT* A_enc = (ushortT*)alloc((size_t)MENC * D_DIM * 2);
  ushortT* bufX = (ushortT*)alloc((size_t)MENC * H_DIM * 2);  // h1 / t2
  ushortT* bufY = (ushortT*)alloc((size_t)MENC * H_DIM * 2);  // h2 / A2
  ushortT* z = (ushortT*)alloc((size_t)MENC * Z_DIM * 2);
  // split-K partial buffer: max(3 planes of MENCxH f32, 8 of MENCxZ)
  float* Pbig = (float*)alloc((size_t)3 * MENC * H_DIM * 4);
  float* wbuf = (float*)alloc((size_t)NROWS * 4);

  const dim3 blk(256);
  const float* nofp = nullptr;
  const ushortT* nobf = nullptr;

  // merged: x -> bf16 + weights (zero loss acc) + all weight transposes
  prep_trans<<<dim3(MENC + 8256), blk, 0, stream>>>(
      x_c, x_nn, A_enc, wbuf, out, We1, We2, We3, Wd1, Wd2, Wd3,
      We1T, We2T, We3T, Wd1T, Wd2T, Wd3T);

  // enc1: h1 = relu(A_enc @ We1 + be1). Split-K S=3 -> 792 blocks.
  gemm32<EP_PART, 128><<<dim3(8, 33, 3), blk, 0, stream>>>(
      A_enc, We1T, nofp, nullptr, Pbig, MENC, H_DIM, D_DIM, D_DIM / 3,
      nobf, nofp, nullptr);
  reduce_lin<3, 1><<<dim3((MENC * H_DIM) / 1024), blk, 0, stream>>>(
      Pbig, be1, bufX, MENC * H_DIM, H_DIM - 1);

  // enc2: h2 = relu(h1 @ We2 + be2). Split-K S=2 -> 528 blocks.
  gemm32<EP_PART, 128><<<dim3(8, 33, 2), blk, 0, stream>>>(
      bufX, We2T, nofp, nullptr, Pbig, MENC, H_DIM, H_DIM, H_DIM / 2,
      nobf, nofp, nullptr);
  reduce_lin<2, 1><<<dim3((MENC * H_DIM) / 1024), blk, 0, stream>>>(
      Pbig, be2, bufY, MENC * H_DIM, H_DIM - 1);

  // z = h2 @ We3 + be3 (N=32): split-K S=8 -> 264 blocks, 4 tiles each
  gemm32<EP_PART, 32><<<dim3(1, 33, 8), blk, 0, stream>>>(
      bufY, We3T, nofp, nullptr, Pbig, MENC, Z_DIM, H_DIM, H_DIM / 8,
      nobf, nofp, nullptr);
  reduce_lin<8, 0><<<dim3((MENC * Z_DIM) / 1024), blk, 0, stream>>>(
      Pbig, be3, z, MENC * Z_DIM, Z_DIM - 1);

  // linearized decoder with frozen center masks (exact for ReLU MLP):
  // dec L1 + fused mask1: A2 = (U1c>0)?U1:0 (neighbors), relu(U1) (centers)
  gemm_sb<EP_MASK1, 64><<<dim3(16, 33), blk, 0, stream>>>(
      z, Wd1T, bd1, bufY, MENC, H_DIM, Z_DIM, nobf, nofp, nullptr);
  // U2 = A2 @ Wd2 + bd2 (partials, all rows). Split-K S=2.
  gemm32<EP_PART, 128><<<dim3(8, 33, 2), blk, 0, stream>>>(
      bufY, Wd2T, nofp, nullptr, Pbig, MENC, H_DIM, H_DIM, H_DIM / 2,
      nobf, nofp, nullptr);
  // t2 = (U2c>0)?U2:0 directly from partials (fused mask2; U2 never stored)
  reduce_lin_mask<2><<<dim3((NROWS * H_DIM) / 1024), blk, 0, stream>>>(
      Pbig, bd2, bufX, NROWS * H_DIM, MENC * H_DIM);
  // loss GEMM: pred = t2 @ Wd3 + bd3, fused weighted-SSE vs bf16 x_nn
  gemm32<EP_LOSS, 128><<<dim3(24, 32, 1), blk, 0, stream>>>(
      bufX, Wd3T, bd3, nullptr, nullptr, NROWS, D_DIM, H_DIM, H_DIM,
      A_enc, wbuf, out);
}